// Round 5
// baseline (272.666 us; speedup 1.0000x reference)
//
#include <hip/hip_runtime.h>

#define NUM_HEADS 16
#define HEAD_DIM  64
#define HIDDEN    1024
#define SEQ       512
#define BATCH     8
#define NBH       128      // BATCH*NUM_HEADS
#define POSN      512      // 2*BUCKET
#define SCALE_F   0.07216878364870323f   // 1/sqrt(3*HEAD_DIM)

typedef __attribute__((ext_vector_type(8))) short  short8;
typedef __attribute__((ext_vector_type(4))) short  short4_t;
typedef __attribute__((ext_vector_type(4))) float  floatx4;

__device__ __forceinline__ float bits2f(short s) {
    union { unsigned u; float f; } x;
    x.u = ((unsigned)(unsigned short)s) << 16;
    return x.f;
}
__device__ __forceinline__ float lo2f(unsigned u) {
    union { unsigned u; float f; } x; x.u = u << 16; return x.f;
}
__device__ __forceinline__ float hi2f(unsigned u) {
    union { unsigned u; float f; } x; x.u = u & 0xffff0000u; return x.f;
}
__device__ __forceinline__ short f2bits(float f) {
    union { float f; unsigned u; } x;
    x.f = f;
    unsigned r = x.u + 0x7fffu + ((x.u >> 16) & 1u);
    return (short)(r >> 16);
}

// ---------------------------------------------------------------------------
// prep: fp32 -> bf16 conversion for inputs and rel_embeddings
// ---------------------------------------------------------------------------
__global__ void conv_pair(const float* __restrict__ a, const float* __restrict__ b,
                          short* __restrict__ oa, short* __restrict__ ob)
{
    const int idx = blockIdx.x * 256 + threadIdx.x;    // one float4 each
    floatx4 va = ((const floatx4*)a)[idx];
    floatx4 vb = ((const floatx4*)b)[idx];
    short4_t ra, rb;
#pragma unroll
    for (int i = 0; i < 4; i++) { ra[i] = f2bits(va[i]); rb[i] = f2bits(vb[i]); }
    ((short4_t*)oa)[idx] = ra;
    ((short4_t*)ob)[idx] = rb;
}

// ---------------------------------------------------------------------------
// prep: transpose + convert the 4 weight matrices [1024][1024] -> bf16 [n][c]
// (o0..o3 are contiguous in ws, so o0 doubles as concat(WqT,WkT,WvT))
// ---------------------------------------------------------------------------
__global__ void wtrans(const float* __restrict__ w0, const float* __restrict__ w1,
                       const float* __restrict__ w2, const float* __restrict__ w3,
                       short* __restrict__ o0, short* __restrict__ o1,
                       short* __restrict__ o2, short* __restrict__ o3)
{
    __shared__ float tile[64][65];
    const int z = blockIdx.z;
    const float* src = (z == 0) ? w0 : (z == 1) ? w1 : (z == 2) ? w2 : w3;
    short*       dst = (z == 0) ? o0 : (z == 1) ? o1 : (z == 2) ? o2 : o3;
    const int c0 = blockIdx.x * 64, n0 = blockIdx.y * 64;
    const int t = threadIdx.x;
#pragma unroll
    for (int j = 0; j < 16; j++) {
        const int e = t + j * 256;
        tile[e >> 6][e & 63] = src[(long)(c0 + (e >> 6)) * 1024 + n0 + (e & 63)];
    }
    __syncthreads();
#pragma unroll
    for (int j = 0; j < 16; j++) {
        const int e = t + j * 256;
        dst[(long)(n0 + (e >> 6)) * 1024 + c0 + (e & 63)] = f2bits(tile[e & 63][e >> 6]);
    }
}

// ---------------------------------------------------------------------------
// prep: 1-D log-bucket table  ftab[delta+511] = clip(bucket(delta)+256, 0, 511)
// ---------------------------------------------------------------------------
__global__ void ftab_build(int* __restrict__ ftab)
{
    const int i = blockIdx.x * 256 + threadIdx.x;
    if (i >= 1023) return;
    const int delta = i - 511;
    const float Cf = (float)log(511.0 / 128.0);
    float absp = (delta < 128 && delta > -128) ? 127.0f : fabsf((float)delta);
    float bucket;
    if (absp <= 128.0f) {
        bucket = (float)delta;
    } else {
        float lp = ceilf((logf(absp * (1.0f / 128.0f)) * 127.0f) / Cf) + 128.0f;
        bucket = (delta > 0) ? lp : -lp;
    }
    int bi = (int)bucket + 256;
    bi = min(max(bi, 0), 511);
    ftab[i] = bi;
}

// ---------------------------------------------------------------------------
// Generic NT GEMM: C[m,n] = sum_k A[m,k] * BT[n,k]   (bf16 in, fp32 acc)
// tile 128x128, BK=64, 256 threads (4 waves, 2x2), 16x16x32 bf16 MFMA
// MODE 1: plain -> bf16 out row-major, batched by z; z<128 uses (A,BT),
//         z>=128 uses (O1,O2) as the A/B pair (merged score GEMMs)
// MODE 2: final -> fp32 out row-major + bias b0 (O0)
// MODE 4: QKV   -> n<1024: Q [b,h,s,d]+b0 (O0); n<2048: K +b1 (O1);
//                  else:   V [b,h,d,s]+b2 (O2)
// MODE 5: posQK -> n<1024: posQ [b,h,p,d]+b0 (O0); else posK +b1 (O1)
// ---------------------------------------------------------------------------
template<int MODE>
__global__ __launch_bounds__(256)
void gemm_nt(const short* __restrict__ A, long aBatch, int lda,
             const short* __restrict__ BT, long bBatch, int ldb,
             void* __restrict__ O0, void* __restrict__ O1, void* __restrict__ O2,
             long oBatch, int ldo,
             const float* __restrict__ b0, const float* __restrict__ b1,
             const float* __restrict__ b2, int Kd)
{
    __shared__ __align__(16) short As[128 * 64];
    __shared__ __align__(16) short Bs[128 * 64];
    const int z = blockIdx.z;
    const short* Ab;
    const short* Bb;
    if (MODE == 1 && z >= 128) {
        Ab = (const short*)O1 + (long)(z - 128) * aBatch;
        Bb = (const short*)O2 + (long)(z - 128) * bBatch;
    } else {
        Ab = A + (long)z * aBatch;
        Bb = BT + (long)z * bBatch;
    }
    const int m0 = blockIdx.x * 128, n0 = blockIdx.y * 128;
    const int t = threadIdx.x;
    const int l = t & 63, w = t >> 6;
    const int wm = w >> 1, wn = w & 1;
    const int lr = l & 15, lg = l >> 4;

    floatx4 acc[4][4];
#pragma unroll
    for (int i = 0; i < 4; i++)
#pragma unroll
        for (int j = 0; j < 4; j++) acc[i][j] = (floatx4){0.f, 0.f, 0.f, 0.f};

    for (int k0 = 0; k0 < Kd; k0 += 64) {
        __syncthreads();
#pragma unroll
        for (int j = 0; j < 4; j++) {
            const int chunk = t + j * 256;   // 1024 chunks of 16B per matrix
            const int row = chunk >> 3;      // 0..127
            const int cc  = chunk & 7;       // logical 16B chunk in row
            const int pc  = cc ^ (row & 7);  // XOR swizzle (bank-conflict-free reads)
            short8 va = *(const short8*)(Ab + (long)(m0 + row) * lda + k0 + cc * 8);
            *(short8*)((char*)As + row * 128 + pc * 16) = va;
            short8 vb = *(const short8*)(Bb + (long)(n0 + row) * ldb + k0 + cc * 8);
            *(short8*)((char*)Bs + row * 128 + pc * 16) = vb;
        }
        __syncthreads();
#pragma unroll
        for (int ks = 0; ks < 2; ks++) {
            short8 af[4], bfr[4];
#pragma unroll
            for (int i = 0; i < 4; i++) {
                const int mr = wm * 64 + i * 16 + lr;
                af[i] = *(const short8*)((char*)As + mr * 128 + (((ks * 4 + lg) ^ (mr & 7)) * 16));
                const int nr = wn * 64 + i * 16 + lr;
                bfr[i] = *(const short8*)((char*)Bs + nr * 128 + (((ks * 4 + lg) ^ (nr & 7)) * 16));
            }
#pragma unroll
            for (int i = 0; i < 4; i++)
#pragma unroll
                for (int j = 0; j < 4; j++)
                    acc[i][j] = __builtin_amdgcn_mfma_f32_16x16x32_bf16(af[i], bfr[j], acc[i][j], 0, 0, 0);
        }
    }

#pragma unroll
    for (int i = 0; i < 4; i++) {
#pragma unroll
        for (int j = 0; j < 4; j++) {
#pragma unroll
            for (int e = 0; e < 4; e++) {
                const int mg = m0 + wm * 64 + i * 16 + lg * 4 + e;
                const int ng = n0 + wn * 64 + j * 16 + lr;
                float v = acc[i][j][e];
                if (MODE == 1) {
                    ((short*)O0)[(long)z * oBatch + (long)mg * ldo + ng] = f2bits(v);
                } else if (MODE == 2) {
                    ((float*)O0)[(long)mg * ldo + ng] = v + b0[ng];
                } else if (MODE == 4) {
                    const int mat = ng >> 10, hh = ng & 1023, h = hh >> 6, d = hh & 63;
                    const int b = mg >> 9, s = mg & 511;
                    v += (mat == 0 ? b0 : mat == 1 ? b1 : b2)[hh];
                    short* dst = (short*)(mat == 0 ? O0 : mat == 1 ? O1 : O2);
                    if (mat == 2)
                        dst[((long)(b * NUM_HEADS + h) * HEAD_DIM + d) * SEQ + s] = f2bits(v);
                    else
                        dst[((long)(b * NUM_HEADS + h) * SEQ + s) * HEAD_DIM + d] = f2bits(v);
                } else {  // MODE 5
                    const int mat = ng >> 10, hh = ng & 1023, h = hh >> 6, d = hh & 63;
                    const int b = mg >> 9, s = mg & 511;
                    v += (mat == 0 ? b0 : b1)[hh];
                    short* dst = (short*)(mat == 0 ? O0 : O1);
                    dst[((long)(b * NUM_HEADS + h) * SEQ + s) * HEAD_DIM + d] = f2bits(v);
                }
            }
        }
    }
}

// ---------------------------------------------------------------------------
// relgather: IN-PLACE relayout  buf[bh][q][k] := buf[bh][f(q-k)][k]
// (bit-exact bf16 copy, no rounding). Block = (k-stripe of 32, bh).
// Safety: the block stages the ENTIRE 512x32 stripe into LDS (32 KB) before
// writing; its write-address set equals its read-address set (same stripe),
// and different blocks touch disjoint stripes -> no cross-block races.
// ---------------------------------------------------------------------------
__global__ __launch_bounds__(256, 4)
void relgather(short* __restrict__ buf, const int* __restrict__ ftab)
{
    __shared__ __align__(16) short pcs[512 * 32];   // 32 KB
    __shared__ short ft[1024];
    const int k0 = blockIdx.x * 32;
    const int bh = blockIdx.y;
    const int t = threadIdx.x;
    for (int i = t; i < 1024; i += 256) ft[i] = (short)((i < 1023) ? ftab[i] : 0);
    short* base = buf + (long)bh * SEQ * POSN;
    // stage: 512 rows x 64B (4 chunks of 16B) = 2048 chunks
#pragma unroll
    for (int j = 0; j < 8; j++) {
        const int chunk = t + j * 256;
        const int row = chunk >> 2, cc = chunk & 3;
        short8 v = *(const short8*)(base + (long)row * POSN + k0 + cc * 8);
        *(short8*)(pcs + row * 32 + cc * 8) = v;
    }
    __syncthreads();
    const int kl = t & 31;
    const int k = k0 + kl;
#pragma unroll 4
    for (int qq = 0; qq < 64; qq++) {
        const int q = (t >> 5) + qq * 8;
        const int fk = (int)ft[q - k + 511];
        base[(long)q * POSN + k] = pcs[fk * 32 + kl];
    }
}

// ---------------------------------------------------------------------------
// Fused attention per (b,h, 16-row q-tile). 4 waves, 3 barriers.
//   QK^T: wave w owns k in [w*128, w*128+128); c2p gather + pre-gathered
//   p2c (G) loads, both 32B-coalesced per 16-lane group, prefetched to regs.
//   softmax: shfl within 16-lane groups + tiny LDS cross-wave combine.
//   PV: wave w owns OUTPUT dims d in [w*16, w*16+16) -> no cross-wave reduce.
// LDS ~18.5 KB; VGPR<=64 -> 8 blocks/CU.
// ---------------------------------------------------------------------------
__global__ __launch_bounds__(256, 8)
void attn_fused(const short* __restrict__ Q, const short* __restrict__ K,
                const short* __restrict__ Vt,
                const short* __restrict__ c2pf, const short* __restrict__ Gp2c,
                const int* __restrict__ ftab,
                short* __restrict__ attnO)
{
    __shared__ __align__(16) short PS[16 * 512];   // swizzled P tile
    __shared__ float red[2][4][16];
    __shared__ short ft[1024];

    // XCD-chunked swizzle: blocks of one bh land on one XCD (4096 % 8 == 0)
    const int lin  = blockIdx.x;
    const int lin2 = (lin & 7) * 512 + (lin >> 3);
    const int bh = lin2 >> 5, qt = lin2 & 31;
    const int q0 = qt * 16;
    const int t = threadIdx.x, l = t & 63, w = t >> 6;
    const int lr = l & 15, lg = l >> 4;
    const long pbase = (long)bh * SEQ * HEAD_DIM;
    const short* Qb  = Q  + pbase;
    const short* Kb  = K  + pbase;
    const short* Vtb = Vt + pbase;
    const short* c2pb = c2pf + (long)bh * SEQ * POSN;
    const short* Gb   = Gp2c + (long)bh * SEQ * SEQ;

    for (int i = t; i < 1024; i += 256) ft[i] = (short)((i < 1023) ? ftab[i] : 0);
    __syncthreads();

    // ---- prefetch gathers into packed u32 regs ----
    unsigned cpk[8][2], gpk[8][2];
#pragma unroll
    for (int nt = 0; nt < 8; nt++) {
        unsigned short cv[4], gv[4];
#pragma unroll
        for (int e = 0; e < 4; e++) {
            const int q = q0 + lg * 4 + e;
            const int k = w * 128 + nt * 16 + lr;
            const int fk = (int)ft[q - k + 511];
            cv[e] = (unsigned short)c2pb[(long)q * POSN + fk];
            gv[e] = (unsigned short)Gb[(long)q * SEQ + k];
        }
        cpk[nt][0] = cv[0] | ((unsigned)cv[1] << 16);
        cpk[nt][1] = cv[2] | ((unsigned)cv[3] << 16);
        gpk[nt][0] = gv[0] | ((unsigned)gv[1] << 16);
        gpk[nt][1] = gv[2] | ((unsigned)gv[3] << 16);
    }

    // ---- Q fragments ----
    short8 aq[2];
#pragma unroll
    for (int ks = 0; ks < 2; ks++)
        aq[ks] = *(const short8*)(Qb + (q0 + lr) * 64 + ks * 32 + lg * 8);

    floatx4 acc[8];
#pragma unroll
    for (int nt = 0; nt < 8; nt++) acc[nt] = (floatx4){0.f, 0.f, 0.f, 0.f};

    // ---- QK^T ----
#pragma unroll
    for (int nt = 0; nt < 8; nt++) {
        const int kr = w * 128 + nt * 16 + lr;
        short8 kb0 = *(const short8*)(Kb + kr * 64 + lg * 8);
        short8 kb1 = *(const short8*)(Kb + kr * 64 + 32 + lg * 8);
        acc[nt] = __builtin_amdgcn_mfma_f32_16x16x32_bf16(aq[0], kb0, acc[nt], 0, 0, 0);
        acc[nt] = __builtin_amdgcn_mfma_f32_16x16x32_bf16(aq[1], kb1, acc[nt], 0, 0, 0);
    }

    // ---- add gathers, scale ----
#pragma unroll
    for (int nt = 0; nt < 8; nt++)
#pragma unroll
        for (int e = 0; e < 4; e++) {
            const float cv = (e & 1) ? hi2f(cpk[nt][e >> 1]) : lo2f(cpk[nt][e >> 1]);
            const float pv = (e & 1) ? hi2f(gpk[nt][e >> 1]) : lo2f(gpk[nt][e >> 1]);
            acc[nt][e] = (acc[nt][e] + cv + pv) * SCALE_F;
        }

    // ---- wave-local row max -> LDS ----
#pragma unroll
    for (int e = 0; e < 4; e++) {
        float m = acc[0][e];
#pragma unroll
        for (int nt = 1; nt < 8; nt++) m = fmaxf(m, acc[nt][e]);
        m = fmaxf(m, __shfl_xor(m, 1));
        m = fmaxf(m, __shfl_xor(m, 2));
        m = fmaxf(m, __shfl_xor(m, 4));
        m = fmaxf(m, __shfl_xor(m, 8));
        red[0][w][lg * 4 + e] = m;
    }
    __syncthreads();

    // ---- combine max, exp, sum, write P tile ----
#pragma unroll
    for (int e = 0; e < 4; e++) {
        const int r = lg * 4 + e;
        const float m = fmaxf(fmaxf(red[0][0][r], red[0][1][r]),
                              fmaxf(red[0][2][r], red[0][3][r]));
        float s = 0.f;
#pragma unroll
        for (int nt = 0; nt < 8; nt++) {
            float p = __expf(acc[nt][e] - m);
            acc[nt][e] = p;
            s += p;
        }
        s += __shfl_xor(s, 1); s += __shfl_xor(s, 2);
        s += __shfl_xor(s, 4); s += __shfl_xor(s, 8);
        red[1][w][r] = s;
#pragma unroll
        for (int nt = 0; nt < 8; nt++) {
            const int kcol = w * 128 + nt * 16 + lr;
            int byte = r * 1024 + kcol * 2;
            byte ^= (r & 7) << 4;
            *(short*)((char*)PS + byte) = f2bits(acc[nt][e]);
        }
    }
    __syncthreads();

    // ---- PV: wave w owns d in [w*16, w*16+16), k-loop over all 512 ----
    floatx4 accO = (floatx4){0.f, 0.f, 0.f, 0.f};
#pragma unroll
    for (int ks = 0; ks < 16; ks++) {
        const int qr = lr;                       // A-frag row = q
        int byte = qr * 1024 + (ks * 32 + lg * 8) * 2;
        byte ^= (qr & 7) << 4;
        short8 pa = *(const short8*)((char*)PS + byte);
        short8 vb = *(const short8*)(Vtb + (long)(w * 16 + lr) * SEQ + ks * 32 + lg * 8);
        accO = __builtin_amdgcn_mfma_f32_16x16x32_bf16(pa, vb, accO, 0, 0, 0);
    }

    // ---- normalize + write ----
    const int b = bh >> 4, h = bh & 15;
#pragma unroll
    for (int e = 0; e < 4; e++) {
        const int r = lg * 4 + e;
        const float rs = red[1][0][r] + red[1][1][r] + red[1][2][r] + red[1][3][r];
        const float v = accO[e] / rs;
        attnO[((long)(b * SEQ + q0 + r)) * HIDDEN + h * HEAD_DIM + w * 16 + lr] = f2bits(v);
    }
}

// ---------------------------------------------------------------------------
extern "C" void kernel_launch(void* const* d_in, const int* in_sizes, int n_in,
                              void* d_out, int out_size, void* d_ws, size_t ws_size,
                              hipStream_t stream)
{
    const float* inputs = (const float*)d_in[0];
    const float* rel    = (const float*)d_in[1];
    const float* Wq     = (const float*)d_in[2];
    const float* bq     = (const float*)d_in[3];
    const float* Wk     = (const float*)d_in[4];
    const float* bk     = (const float*)d_in[5];
    const float* Wv     = (const float*)d_in[6];
    const float* bv     = (const float*)d_in[7];
    const float* Wo     = (const float*)d_in[8];
    const float* bo     = (const float*)d_in[9];
    float* out = (float*)d_out;

    char* ws = (char*)d_ws;
    size_t off = 0;
    auto alloc = [&](size_t bytes) -> char* {
        char* p = ws + off;
        off += (bytes + 255) & ~(size_t)255;
        return p;
    };
    short* inA   = (short*)alloc(4194304ull * 2);
    short* inRel = (short*)alloc(4194304ull * 2);
    short* WqT   = (short*)alloc(1048576ull * 2);   // WqT/WkT/WvT contiguous ->
    short* WkT   = (short*)alloc(1048576ull * 2);   // concat B for fused GEMMs
    short* WvT   = (short*)alloc(1048576ull * 2);
    short* WoT   = (short*)alloc(1048576ull * 2);
    short* Qw    = (short*)alloc(4194304ull * 2);
    short* Kw    = (short*)alloc(4194304ull * 2);
    short* Vtw   = (short*)alloc(4194304ull * 2);
    short* posQw = (short*)alloc(4194304ull * 2);
    short* posKw = (short*)alloc(4194304ull * 2);
    short* c2pW  = (short*)alloc(33554432ull * 2);  // c2pW/p2cW contiguous ->
    short* p2cW  = (short*)alloc(33554432ull * 2);  // merged score-GEMM output
    short* attnW = (short*)alloc(4194304ull * 2);
    int*   ftabW = (int*)alloc(4096);
    // total ws: ~209.7 MB (round-3 footprint, known-safe; round-4's extra
    // 67 MB G buffer overflowed ws -> in-place relgather instead)

    // prep
    conv_pair<<<4096, 256, 0, stream>>>(inputs, rel, inA, inRel);
    wtrans<<<dim3(16, 16, 4), 256, 0, stream>>>(Wq, Wk, Wv, Wo, WqT, WkT, WvT, WoT);
    ftab_build<<<4, 256, 0, stream>>>(ftabW);

    // fused QKV projection (N=3072) and posQ/posK projection (N=2048)
    gemm_nt<4><<<dim3(32, 24), 256, 0, stream>>>(inA, 0, 1024, WqT, 0, 1024,
                                                 Qw, Kw, Vtw, 0, 0, bq, bk, bv, 1024);
    gemm_nt<5><<<dim3(32, 16), 256, 0, stream>>>(inRel, 0, 1024, WqT, 0, 1024,
                                                 posQw, posKw, nullptr, 0, 0, bq, bk, nullptr, 1024);

    // merged score GEMMs: z<128 -> c2p = Q@posK^T; z>=128 -> p2cT = posQ@K^T
    gemm_nt<1><<<dim3(4, 4, 256), 256, 0, stream>>>(Qw, 32768, 64, posKw, 32768, 64,
                                                    c2pW, posQw, Kw, 262144, 512,
                                                    nullptr, nullptr, nullptr, 64);

    // in-place pre-gather: p2cW[bh][q][k] := p2cW[bh][f(q-k)][k]
    relgather<<<dim3(16, 128), 256, 0, stream>>>(p2cW, ftabW);

    // fused scores+gather+softmax+PV
    attn_fused<<<4096, 256, 0, stream>>>(Qw, Kw, Vtw, c2pW, p2cW, ftabW, attnW);

    // output projection (fp32 out + bias)
    gemm_nt<2><<<dim3(32, 8), 256, 0, stream>>>(attnW, 0, 1024, WoT, 0, 1024,
                                                out, nullptr, nullptr, 0, 1024, bo, nullptr, nullptr, 1024);
}

// Round 6
// 259.365 us; speedup vs baseline: 1.0513x; 1.0513x over previous
//
#include <hip/hip_runtime.h>

#define NUM_HEADS 16
#define HEAD_DIM  64
#define HIDDEN    1024
#define SEQ       512
#define BATCH     8
#define NBH       128      // BATCH*NUM_HEADS
#define POSN      512      // 2*BUCKET
#define SCALE_F   0.07216878364870323f   // 1/sqrt(3*HEAD_DIM)

typedef __attribute__((ext_vector_type(8))) short  short8;
typedef __attribute__((ext_vector_type(4))) short  short4_t;
typedef __attribute__((ext_vector_type(4))) float  floatx4;

__device__ __forceinline__ float bits2f(short s) {
    union { unsigned u; float f; } x;
    x.u = ((unsigned)(unsigned short)s) << 16;
    return x.f;
}
__device__ __forceinline__ short f2bits(float f) {
    union { float f; unsigned u; } x;
    x.f = f;
    unsigned r = x.u + 0x7fffu + ((x.u >> 16) & 1u);
    return (short)(r >> 16);
}

// ---------------------------------------------------------------------------
// prep: fp32 -> bf16 conversion for inputs and rel_embeddings
// ---------------------------------------------------------------------------
__global__ void conv_pair(const float* __restrict__ a, const float* __restrict__ b,
                          short* __restrict__ oa, short* __restrict__ ob)
{
    const int idx = blockIdx.x * 256 + threadIdx.x;    // one float4 each
    floatx4 va = ((const floatx4*)a)[idx];
    floatx4 vb = ((const floatx4*)b)[idx];
    short4_t ra, rb;
#pragma unroll
    for (int i = 0; i < 4; i++) { ra[i] = f2bits(va[i]); rb[i] = f2bits(vb[i]); }
    ((short4_t*)oa)[idx] = ra;
    ((short4_t*)ob)[idx] = rb;
}

// ---------------------------------------------------------------------------
// prep: transpose + convert the 4 weight matrices [1024][1024] -> bf16 [n][c]
// ---------------------------------------------------------------------------
__global__ void wtrans(const float* __restrict__ w0, const float* __restrict__ w1,
                       const float* __restrict__ w2, const float* __restrict__ w3,
                       short* __restrict__ o0, short* __restrict__ o1,
                       short* __restrict__ o2, short* __restrict__ o3)
{
    __shared__ float tile[64][65];
    const int z = blockIdx.z;
    const float* src = (z == 0) ? w0 : (z == 1) ? w1 : (z == 2) ? w2 : w3;
    short*       dst = (z == 0) ? o0 : (z == 1) ? o1 : (z == 2) ? o2 : o3;
    const int c0 = blockIdx.x * 64, n0 = blockIdx.y * 64;
    const int t = threadIdx.x;
#pragma unroll
    for (int j = 0; j < 16; j++) {
        const int e = t + j * 256;
        tile[e >> 6][e & 63] = src[(long)(c0 + (e >> 6)) * 1024 + n0 + (e & 63)];
    }
    __syncthreads();
#pragma unroll
    for (int j = 0; j < 16; j++) {
        const int e = t + j * 256;
        dst[(long)(n0 + (e >> 6)) * 1024 + c0 + (e & 63)] = f2bits(tile[e & 63][e >> 6]);
    }
}

// ---------------------------------------------------------------------------
// prep: 1-D log-bucket table  ftab[delta+511] = clip(bucket(delta)+256, 0, 511)
// ---------------------------------------------------------------------------
__global__ void ftab_build(int* __restrict__ ftab)
{
    const int i = blockIdx.x * 256 + threadIdx.x;
    if (i >= 1023) return;
    const int delta = i - 511;
    const float Cf = (float)log(511.0 / 128.0);
    float absp = (delta < 128 && delta > -128) ? 127.0f : fabsf((float)delta);
    float bucket;
    if (absp <= 128.0f) {
        bucket = (float)delta;
    } else {
        float lp = ceilf((logf(absp * (1.0f / 128.0f)) * 127.0f) / Cf) + 128.0f;
        bucket = (delta > 0) ? lp : -lp;
    }
    int bi = (int)bucket + 256;
    bi = min(max(bi, 0), 511);
    ftab[i] = bi;
}

// ---------------------------------------------------------------------------
// Generic NT GEMM: C[m,n] = sum_k A[m,k] * BT[n,k]   (bf16 in, fp32 acc)
// tile 128x128, BK=64, 256 threads (4 waves, 2x2), 16x16x32 bf16 MFMA
// MODE 1: plain -> bf16 out row-major, batched by z; z<128 uses (A,BT),
//         z>=128 uses (O1,O2) as the A/B pair (merged score GEMMs)
// MODE 2: final -> fp32 out row-major + bias b0 (O0)
// MODE 4: QKV   -> n<1024: Q [b,h,s,d]+b0 (O0); n<2048: K +b1 (O1);
//                  else:   V [b,h,d,s]+b2 (O2)
// MODE 5: posQK -> n<1024: posQ [b,h,p,d]+b0 (O0); else posK +b1 (O1)
// ---------------------------------------------------------------------------
template<int MODE>
__global__ __launch_bounds__(256)
void gemm_nt(const short* __restrict__ A, long aBatch, int lda,
             const short* __restrict__ BT, long bBatch, int ldb,
             void* __restrict__ O0, void* __restrict__ O1, void* __restrict__ O2,
             long oBatch, int ldo,
             const float* __restrict__ b0, const float* __restrict__ b1,
             const float* __restrict__ b2, int Kd)
{
    __shared__ __align__(16) short As[128 * 64];
    __shared__ __align__(16) short Bs[128 * 64];
    const int z = blockIdx.z;
    const short* Ab;
    const short* Bb;
    if (MODE == 1 && z >= 128) {
        Ab = (const short*)O1 + (long)(z - 128) * aBatch;
        Bb = (const short*)O2 + (long)(z - 128) * bBatch;
    } else {
        Ab = A + (long)z * aBatch;
        Bb = BT + (long)z * bBatch;
    }
    const int m0 = blockIdx.x * 128, n0 = blockIdx.y * 128;
    const int t = threadIdx.x;
    const int l = t & 63, w = t >> 6;
    const int wm = w >> 1, wn = w & 1;
    const int lr = l & 15, lg = l >> 4;

    floatx4 acc[4][4];
#pragma unroll
    for (int i = 0; i < 4; i++)
#pragma unroll
        for (int j = 0; j < 4; j++) acc[i][j] = (floatx4){0.f, 0.f, 0.f, 0.f};

    for (int k0 = 0; k0 < Kd; k0 += 64) {
        __syncthreads();
#pragma unroll
        for (int j = 0; j < 4; j++) {
            const int chunk = t + j * 256;   // 1024 chunks of 16B per matrix
            const int row = chunk >> 3;      // 0..127
            const int cc  = chunk & 7;       // logical 16B chunk in row
            const int pc  = cc ^ (row & 7);  // XOR swizzle (bank-conflict-free reads)
            short8 va = *(const short8*)(Ab + (long)(m0 + row) * lda + k0 + cc * 8);
            *(short8*)((char*)As + row * 128 + pc * 16) = va;
            short8 vb = *(const short8*)(Bb + (long)(n0 + row) * ldb + k0 + cc * 8);
            *(short8*)((char*)Bs + row * 128 + pc * 16) = vb;
        }
        __syncthreads();
#pragma unroll
        for (int ks = 0; ks < 2; ks++) {
            short8 af[4], bfr[4];
#pragma unroll
            for (int i = 0; i < 4; i++) {
                const int mr = wm * 64 + i * 16 + lr;
                af[i] = *(const short8*)((char*)As + mr * 128 + (((ks * 4 + lg) ^ (mr & 7)) * 16));
                const int nr = wn * 64 + i * 16 + lr;
                bfr[i] = *(const short8*)((char*)Bs + nr * 128 + (((ks * 4 + lg) ^ (nr & 7)) * 16));
            }
#pragma unroll
            for (int i = 0; i < 4; i++)
#pragma unroll
                for (int j = 0; j < 4; j++)
                    acc[i][j] = __builtin_amdgcn_mfma_f32_16x16x32_bf16(af[i], bfr[j], acc[i][j], 0, 0, 0);
        }
    }

#pragma unroll
    for (int i = 0; i < 4; i++) {
#pragma unroll
        for (int j = 0; j < 4; j++) {
#pragma unroll
            for (int e = 0; e < 4; e++) {
                const int mg = m0 + wm * 64 + i * 16 + lg * 4 + e;
                const int ng = n0 + wn * 64 + j * 16 + lr;
                float v = acc[i][j][e];
                if (MODE == 1) {
                    ((short*)O0)[(long)z * oBatch + (long)mg * ldo + ng] = f2bits(v);
                } else if (MODE == 2) {
                    ((float*)O0)[(long)mg * ldo + ng] = v + b0[ng];
                } else if (MODE == 4) {
                    const int mat = ng >> 10, hh = ng & 1023, h = hh >> 6, d = hh & 63;
                    const int b = mg >> 9, s = mg & 511;
                    v += (mat == 0 ? b0 : mat == 1 ? b1 : b2)[hh];
                    short* dst = (short*)(mat == 0 ? O0 : mat == 1 ? O1 : O2);
                    if (mat == 2)
                        dst[((long)(b * NUM_HEADS + h) * HEAD_DIM + d) * SEQ + s] = f2bits(v);
                    else
                        dst[((long)(b * NUM_HEADS + h) * SEQ + s) * HEAD_DIM + d] = f2bits(v);
                } else {  // MODE 5
                    const int mat = ng >> 10, hh = ng & 1023, h = hh >> 6, d = hh & 63;
                    const int b = mg >> 9, s = mg & 511;
                    v += (mat == 0 ? b0 : b1)[hh];
                    short* dst = (short*)(mat == 0 ? O0 : O1);
                    dst[((long)(b * NUM_HEADS + h) * SEQ + s) * HEAD_DIM + d] = f2bits(v);
                }
            }
        }
    }
}

// ---------------------------------------------------------------------------
// relgather: IN-PLACE relayout  buf[bh][q][k] := buf[bh][f(q-k)][k]
// (bit-exact bf16 copy). Block = (k-stripe of 32, bh). Stage the whole
// 512x32 stripe in LDS first (read-set == write-set -> in-place safe; stripes
// disjoint across blocks). Writes are VECTOR short8 (8 gathered shorts packed
// per store) -- round-5 version's 64 scalar stores/thread were the bottleneck.
// ---------------------------------------------------------------------------
__global__ __launch_bounds__(256, 4)
void relgather(short* __restrict__ buf, const int* __restrict__ ftab)
{
    __shared__ __align__(16) short pcs[512 * 32];   // 32 KB
    __shared__ short ft[1024];
    const int k0 = blockIdx.x * 32;
    const int bh = blockIdx.y;
    const int t = threadIdx.x;
    for (int i = t; i < 1024; i += 256) ft[i] = (short)((i < 1023) ? ftab[i] : 0);
    short* base = buf + (long)bh * SEQ * POSN;
    // stage: 512 rows x 64B (4 chunks of 16B) = 2048 chunks
#pragma unroll
    for (int j = 0; j < 8; j++) {
        const int chunk = t + j * 256;
        const int row = chunk >> 2, cc = chunk & 3;
        short8 v = *(const short8*)(base + (long)row * POSN + k0 + cc * 8);
        *(short8*)(pcs + row * 32 + cc * 8) = v;
    }
    __syncthreads();
    // write: 512 q-rows x 4 chunks of 8 = 2048 tasks, vector stores
#pragma unroll
    for (int j = 0; j < 8; j++) {
        const int task = t + j * 256;
        const int q = task >> 2, kc = task & 3;
        short8 v;
#pragma unroll
        for (int i = 0; i < 8; i++) {
            const int k = k0 + kc * 8 + i;
            const int fk = (int)ft[q - k + 511];
            v[i] = pcs[fk * 32 + kc * 8 + i];
        }
        *(short8*)(base + (long)q * POSN + k0 + kc * 8) = v;
    }
}

// ---------------------------------------------------------------------------
// Fused attention per (b,h, 16-row q-tile). 4 waves.
//   Stage c2p rows (gathered from LDS via ftab) and pre-gathered p2c' rows
//   (linear) -- ALL global traffic is short8 vectors; zero scalar global ops.
//   QK^T: wave w owns k in [w*128, w*128+128).
//   softmax: shfl within 16-lane groups + tiny LDS cross-wave combine.
//   PV: wave w owns OUTPUT dims d in [w*16, w*16+16) -> no cross-wave reduce.
//   P-tile LDS aliases the c2p staging buffer (barrier-separated phases).
// LDS ~35 KB -> 4 blocks/CU (16 waves, 50% occ).
// ---------------------------------------------------------------------------
__global__ __launch_bounds__(256, 4)
void attn_fused(const short* __restrict__ Q, const short* __restrict__ K,
                const short* __restrict__ Vt,
                const short* __restrict__ c2pf, const short* __restrict__ Gp2c,
                const int* __restrict__ ftab,
                short* __restrict__ attnO)
{
    __shared__ __align__(16) short c2pS[16 * 512];  // phase 1: c2p rows; phase 2: P tile
    __shared__ __align__(16) short p2cS[16 * 512];  // p2c' rows (linear [q][k])
    __shared__ float red[2][4][16];
    __shared__ short ft[1024];

    // XCD-chunked swizzle: blocks of one bh land on one XCD (4096 % 8 == 0)
    const int lin  = blockIdx.x;
    const int lin2 = (lin & 7) * 512 + (lin >> 3);
    const int bh = lin2 >> 5, qt = lin2 & 31;
    const int q0 = qt * 16;
    const int t = threadIdx.x, l = t & 63, w = t >> 6;
    const int lr = l & 15, lg = l >> 4;
    const long pbase = (long)bh * SEQ * HEAD_DIM;
    const short* Qb  = Q  + pbase;
    const short* Kb  = K  + pbase;
    const short* Vtb = Vt + pbase;
    const short* c2pb = c2pf + (long)bh * SEQ * POSN;
    const short* Gb   = Gp2c + (long)bh * SEQ * SEQ;

    for (int i = t; i < 1024; i += 256) ft[i] = (short)((i < 1023) ? ftab[i] : 0);
    // stage 16 c2p rows + 16 p2c' rows: 1024 short8 chunks each, 4 iters
#pragma unroll
    for (int j = 0; j < 4; j++) {
        const int chunk = t + j * 256;
        const int row = chunk >> 6, cc = chunk & 63;
        *(short8*)(c2pS + row * 512 + cc * 8) =
            *(const short8*)(c2pb + (long)(q0 + row) * POSN + cc * 8);
        *(short8*)(p2cS + row * 512 + cc * 8) =
            *(const short8*)(Gb + (long)(q0 + row) * SEQ + cc * 8);
    }

    // ---- Q fragments (independent of LDS staging) ----
    short8 aq[2];
#pragma unroll
    for (int ks = 0; ks < 2; ks++)
        aq[ks] = *(const short8*)(Qb + (q0 + lr) * 64 + ks * 32 + lg * 8);

    floatx4 acc[8];
#pragma unroll
    for (int nt = 0; nt < 8; nt++) acc[nt] = (floatx4){0.f, 0.f, 0.f, 0.f};

    // ---- QK^T (K straight from global/L2) ----
#pragma unroll
    for (int nt = 0; nt < 8; nt++) {
        const int kr = w * 128 + nt * 16 + lr;
        short8 kb0 = *(const short8*)(Kb + kr * 64 + lg * 8);
        short8 kb1 = *(const short8*)(Kb + kr * 64 + 32 + lg * 8);
        acc[nt] = __builtin_amdgcn_mfma_f32_16x16x32_bf16(aq[0], kb0, acc[nt], 0, 0, 0);
        acc[nt] = __builtin_amdgcn_mfma_f32_16x16x32_bf16(aq[1], kb1, acc[nt], 0, 0, 0);
    }

    __syncthreads();   // staging complete

    // ---- add c2p (LDS gather) + p2c (LDS linear), scale ----
#pragma unroll
    for (int nt = 0; nt < 8; nt++) {
        const int k = w * 128 + nt * 16 + lr;
#pragma unroll
        for (int e = 0; e < 4; e++) {
            const int r = lg * 4 + e;
            const int fk = (int)ft[q0 + r - k + 511];
            acc[nt][e] = (acc[nt][e] + bits2f(c2pS[r * 512 + fk])
                                     + bits2f(p2cS[r * 512 + k])) * SCALE_F;
        }
    }

    // ---- wave-local row max -> LDS ----
#pragma unroll
    for (int e = 0; e < 4; e++) {
        float m = acc[0][e];
#pragma unroll
        for (int nt = 1; nt < 8; nt++) m = fmaxf(m, acc[nt][e]);
        m = fmaxf(m, __shfl_xor(m, 1));
        m = fmaxf(m, __shfl_xor(m, 2));
        m = fmaxf(m, __shfl_xor(m, 4));
        m = fmaxf(m, __shfl_xor(m, 8));
        red[0][w][lg * 4 + e] = m;
    }
    __syncthreads();   // also separates last c2pS read from P-tile writes

    // ---- combine max, exp, sum, write P tile (aliases c2pS) ----
#pragma unroll
    for (int e = 0; e < 4; e++) {
        const int r = lg * 4 + e;
        const float m = fmaxf(fmaxf(red[0][0][r], red[0][1][r]),
                              fmaxf(red[0][2][r], red[0][3][r]));
        float s = 0.f;
#pragma unroll
        for (int nt = 0; nt < 8; nt++) {
            float p = __expf(acc[nt][e] - m);
            acc[nt][e] = p;
            s += p;
        }
        s += __shfl_xor(s, 1); s += __shfl_xor(s, 2);
        s += __shfl_xor(s, 4); s += __shfl_xor(s, 8);
        red[1][w][r] = s;
#pragma unroll
        for (int nt = 0; nt < 8; nt++) {
            const int kcol = w * 128 + nt * 16 + lr;
            int byte = r * 1024 + kcol * 2;
            byte ^= (r & 7) << 4;
            *(short*)((char*)c2pS + byte) = f2bits(acc[nt][e]);
        }
    }
    __syncthreads();

    // ---- PV: wave w owns d in [w*16, w*16+16), k-loop over all 512 ----
    floatx4 accO = (floatx4){0.f, 0.f, 0.f, 0.f};
#pragma unroll
    for (int ks = 0; ks < 16; ks++) {
        const int qr = lr;                       // A-frag row = q
        int byte = qr * 1024 + (ks * 32 + lg * 8) * 2;
        byte ^= (qr & 7) << 4;
        short8 pa = *(const short8*)((char*)c2pS + byte);
        short8 vb = *(const short8*)(Vtb + (long)(w * 16 + lr) * SEQ + ks * 32 + lg * 8);
        accO = __builtin_amdgcn_mfma_f32_16x16x32_bf16(pa, vb, accO, 0, 0, 0);
    }

    // ---- normalize + write ----
    const int b = bh >> 4, h = bh & 15;
#pragma unroll
    for (int e = 0; e < 4; e++) {
        const int r = lg * 4 + e;
        const float rs = red[1][0][r] + red[1][1][r] + red[1][2][r] + red[1][3][r];
        const float v = accO[e] / rs;
        attnO[((long)(b * SEQ + q0 + r)) * HIDDEN + h * HEAD_DIM + w * 16 + lr] = f2bits(v);
    }
}

// ---------------------------------------------------------------------------
extern "C" void kernel_launch(void* const* d_in, const int* in_sizes, int n_in,
                              void* d_out, int out_size, void* d_ws, size_t ws_size,
                              hipStream_t stream)
{
    const float* inputs = (const float*)d_in[0];
    const float* rel    = (const float*)d_in[1];
    const float* Wq     = (const float*)d_in[2];
    const float* bq     = (const float*)d_in[3];
    const float* Wk     = (const float*)d_in[4];
    const float* bk     = (const float*)d_in[5];
    const float* Wv     = (const float*)d_in[6];
    const float* bv     = (const float*)d_in[7];
    const float* Wo     = (const float*)d_in[8];
    const float* bo     = (const float*)d_in[9];
    float* out = (float*)d_out;

    char* ws = (char*)d_ws;
    size_t off = 0;
    auto alloc = [&](size_t bytes) -> char* {
        char* p = ws + off;
        off += (bytes + 255) & ~(size_t)255;
        return p;
    };
    short* inA   = (short*)alloc(4194304ull * 2);
    short* inRel = (short*)alloc(4194304ull * 2);
    short* WqT   = (short*)alloc(1048576ull * 2);   // WqT/WkT/WvT contiguous ->
    short* WkT   = (short*)alloc(1048576ull * 2);   // concat B for fused GEMMs
    short* WvT   = (short*)alloc(1048576ull * 2);
    short* WoT   = (short*)alloc(1048576ull * 2);
    short* Qw    = (short*)alloc(4194304ull * 2);
    short* Kw    = (short*)alloc(4194304ull * 2);
    short* Vtw   = (short*)alloc(4194304ull * 2);
    short* posQw = (short*)alloc(4194304ull * 2);
    short* posKw = (short*)alloc(4194304ull * 2);
    short* c2pW  = (short*)alloc(33554432ull * 2);  // c2pW/p2cW contiguous ->
    short* p2cW  = (short*)alloc(33554432ull * 2);  // merged score-GEMM output
    short* attnW = (short*)alloc(4194304ull * 2);
    int*   ftabW = (int*)alloc(4096);
    // total ws: ~209.7 MB (known-safe footprint)

    // prep
    conv_pair<<<4096, 256, 0, stream>>>(inputs, rel, inA, inRel);
    wtrans<<<dim3(16, 16, 4), 256, 0, stream>>>(Wq, Wk, Wv, Wo, WqT, WkT, WvT, WoT);
    ftab_build<<<4, 256, 0, stream>>>(ftabW);

    // fused QKV projection (N=3072) and posQ/posK projection (N=2048)
    gemm_nt<4><<<dim3(32, 24), 256, 0, stream>>>(inA, 0, 1024, WqT, 0, 1024,
                                                 Qw, Kw, Vtw, 0, 0, bq, bk, bv, 1024);
    gemm_nt<5><<<dim3(32, 16), 256, 0, stream>>>(inRel, 0, 1024, WqT, 0, 1024,
                                                 posQw, posKw, nullptr, 0, 0, bq, bk, nullptr, 1024);

    // merged score GEMMs: z<128 -> c2p = Q@posK^T; z>=128 -> p2cT = posQ@K^T
    gemm_nt<1><<<dim3(4, 4, 256), 256, 0, stream>>>(Qw, 32768, 64, posKw, 32768, 64,
                                                    c2pW, posQw, Kw, 262144, 512,
                                                    nullptr, nullptr, nullptr, 64);

    // in-place pre-gather: p2cW[bh][q][k] := p2cW[bh][f(q-k)][k]  (vector writes)
    relgather<<<dim3(16, 128), 256, 0, stream>>>(p2cW, ftabW);

    // fused scores+gather+softmax+PV (all-vector global traffic)
    attn_fused<<<4096, 256, 0, stream>>>(Qw, Kw, Vtw, c2pW, p2cW, ftabW, attnW);

    // output projection (fp32 out + bias)
    gemm_nt<2><<<dim3(32, 8), 256, 0, stream>>>(attnW, 0, 1024, WoT, 0, 1024,
                                                out, nullptr, nullptr, 0, 1024, bo, nullptr, nullptr, 1024);
}